// Round 6
// baseline (351.817 us; speedup 1.0000x reference)
//
#include <hip/hip_runtime.h>
#include <hip/hip_cooperative_groups.h>

namespace cg = cooperative_groups;

typedef unsigned long long u64;
typedef unsigned int u32;
typedef __attribute__((ext_vector_type(8))) short short8;
typedef __attribute__((ext_vector_type(4))) float f32x4;

#define N_ROWS 32768
#define DIM    256
#define NE     1024

// out layout (float offsets)
#define O_ZQ   0
#define O_LOSS 8388608
#define O_IDX  8388609
#define O_NCB  8421377
#define O_NCS  8683521
#define O_NES  8684545

// ws layout (float offsets)
#define OFF_LOSS   0
#define OFF_N      1
#define OFF_CSQ    64
#define OFF_CNT    1088
#define OFF_FILL   2112      // int[1024]
#define OFF_BASE   3200      // int[1024]
#define OFF_IDX    4224      // int[32768]
#define OFF_BUCKET 36992     // int[32768]
#define OFF_KEY    69888     // u64[32768]
#define OFF_CB16   135424    // ushort[262144] = 512KB bf16 codebook

#define MARGIN   2.0f
#define LIST_CAP 3072

__device__ __forceinline__ unsigned short bf16rne(float x) {
    u32 b = __float_as_uint(x);
    return (unsigned short)((b + 0x7FFFu + ((b >> 16) & 1u)) >> 16);
}

// ---------------- prep: zero stats/keys/bsum + csq + bf16 codebook ----------------
__global__ __launch_bounds__(256) void prep_kernel(const float* __restrict__ cb,
                                                   float* __restrict__ ws,
                                                   float* __restrict__ out_nes) {
    const int tid = threadIdx.x, b = blockIdx.x;
    const int g = b * 256 + tid;

#pragma unroll
    for (int j = 0; j < 4; ++j) out_nes[g + j * 65536] = 0.f;
    if (g < N_ROWS) ((u64*)(ws + OFF_KEY))[g] = ~0ull;
    if (g < 2048) ws[OFF_CNT + g] = 0.f;           // CNT + FILL
    if (g == 0) ws[OFF_LOSS] = 0.f;

    const int e = b * 4 + (tid >> 6);
    const int lane = tid & 63;
    float4 v = *(const float4*)(cb + (size_t)e * DIM + lane * 4);
    ushort4 h;
    h.x = bf16rne(v.x); h.y = bf16rne(v.y); h.z = bf16rne(v.z); h.w = bf16rne(v.w);
    *(ushort4*)((unsigned short*)(ws + OFF_CB16) + (size_t)e * DIM + lane * 4) = h;
    float s = v.x * v.x + v.y * v.y + v.z * v.z + v.w * v.w;
#pragma unroll
    for (int off = 32; off >= 1; off >>= 1) s += __shfl_down(s, off, 64);
    if (lane == 0) ws[OFF_CSQ + e] = s;
}

// ---------------- main: MFMA distances + margin refine + idx/counts/loss ----------------
__global__ __launch_bounds__(512, 2) void vq_main(const float* __restrict__ z,
                                                  const float* __restrict__ cb,
                                                  float* __restrict__ ws,
                                                  float* __restrict__ out_idx) {
    __shared__ unsigned short zs[128][256];   // 64KB, cols XOR-swizzled by 8*(row&15)
    __shared__ unsigned short cbs[256][128];  // 64KB, same swizzle
    __shared__ float csq_s[NE];               // 4KB
    __shared__ u32   list[LIST_CAP];          // 12KB
    __shared__ int   lcnt;
    __shared__ float zsq_s[128];
    __shared__ float lred[8];

    const int tid  = threadIdx.x;
    const int row0 = blockIdx.x * 128;
    const unsigned short* cb16 = (const unsigned short*)(ws + OFF_CB16);
    u64* keys = (u64*)(ws + OFF_KEY);
    int* wsi  = (int*)ws;

    // ---- prologue: issue cbs tile-0 loads first (they fly during z staging)
    const int sr_c = tid >> 4;            // 0..31
    const int lk_c = (tid & 15) * 8;
    short8 stg[8];
#pragma unroll
    for (int s = 0; s < 8; ++s)
        stg[s] = *(const short8*)(cb16 + (size_t)(s * 32 + sr_c) * DIM + lk_c);

    if (tid == 0) lcnt = 0;
    if (tid < 128) zsq_s[tid] = 0.f;
    csq_s[tid]       = ws[OFF_CSQ + tid];
    csq_s[tid + 512] = ws[OFF_CSQ + tid + 512];
    __syncthreads();   // zsq_s zeroed before atomic accumulation

    // ---- stage z tile f32 -> bf16 (+ per-row ||z||^2 accumulation)
#pragma unroll
    for (int sweep = 0; sweep < 8; ++sweep) {
        int fi = sweep * 4096 + tid * 8;
        int r = fi >> 8, c = fi & 255;
        const float4* src = (const float4*)(z + (size_t)row0 * DIM + fi);
        float4 v0 = src[0], v1 = src[1];
        short8 p;
        p[0] = (short)bf16rne(v0.x); p[1] = (short)bf16rne(v0.y);
        p[2] = (short)bf16rne(v0.z); p[3] = (short)bf16rne(v0.w);
        p[4] = (short)bf16rne(v1.x); p[5] = (short)bf16rne(v1.y);
        p[6] = (short)bf16rne(v1.z); p[7] = (short)bf16rne(v1.w);
        *(short8*)&zs[r][c ^ (8 * (r & 15))] = p;
        float sq = v0.x * v0.x + v0.y * v0.y + v0.z * v0.z + v0.w * v0.w
                 + v1.x * v1.x + v1.y * v1.y + v1.z * v1.z + v1.w * v1.w;
        atomicAdd(&zsq_s[r], sq);
    }

    const int wid = tid >> 6, lane = tid & 63;
    const int wm = wid >> 2, wn = wid & 3;          // wave grid 2M x 4N
    const int l15 = lane & 15, l4 = lane >> 4;
    const int arow_base = wm * 64;
    const int swz = 8 * l15;

    float runmin[4][4];
#pragma unroll
    for (int m = 0; m < 4; ++m)
#pragma unroll
        for (int rg = 0; rg < 4; ++rg) runmin[m][rg] = 3.4e38f;

    f32x4 acc[4][4];

    // ---- 8 phases (4 chunks x 2 k-halves), cbs staged one phase ahead
    for (int phase = 0; phase < 8; ++phase) {
        const int chunk = phase >> 1, kh = phase & 1;
        const int e0 = chunk << 8;
        if (kh == 0) {
#pragma unroll
            for (int m = 0; m < 4; ++m)
#pragma unroll
                for (int n = 0; n < 4; ++n) acc[m][n] = (f32x4){0.f, 0.f, 0.f, 0.f};
        }
        __syncthreads();   // previous tile's readers done
#pragma unroll
        for (int s = 0; s < 8; ++s) {          // ds_write staged regs (vmcnt wait here)
            int r = s * 32 + sr_c;
            *(short8*)&cbs[r][lk_c ^ (8 * (r & 15))] = stg[s];
        }
        __syncthreads();   // tile visible
        if (phase < 7) {                        // issue next tile's loads (async)
            int np = phase + 1;
            int nbase = (np >> 1) * 256, nkh = np & 1;
#pragma unroll
            for (int s = 0; s < 8; ++s)
                stg[s] = *(const short8*)(cb16 + (size_t)(nbase + s * 32 + sr_c) * DIM
                                          + nkh * 128 + lk_c);
        }
#pragma unroll
        for (int ks = 0; ks < 4; ++ks) {
            short8 a[4], bfr[4];
            int acol = kh * 128 + ks * 32 + 8 * l4;
            int bcol = ks * 32 + 8 * l4;
#pragma unroll
            for (int m = 0; m < 4; ++m)
                a[m] = *(const short8*)&zs[arow_base + m * 16 + l15][acol ^ swz];
#pragma unroll
            for (int n = 0; n < 4; ++n)
                bfr[n] = *(const short8*)&cbs[wn * 64 + n * 16 + l15][bcol ^ swz];
#pragma unroll
            for (int m = 0; m < 4; ++m)
#pragma unroll
                for (int n = 0; n < 4; ++n)
                    acc[m][n] = __builtin_amdgcn_mfma_f32_16x16x32_bf16(
                        a[m], bfr[n], acc[m][n], 0, 0, 0);
        }
        if (kh == 1) {
            // ---- chunk epilogue: per-row running min + margin push
            float cq[4];
#pragma unroll
            for (int n = 0; n < 4; ++n) cq[n] = csq_s[e0 + wn * 64 + n * 16 + l15];
#pragma unroll
            for (int m = 0; m < 4; ++m) {
#pragma unroll
                for (int rg = 0; rg < 4; ++rg) {
                    float cmin = 3.4e38f;
#pragma unroll
                    for (int n = 0; n < 4; ++n)
                        cmin = fminf(cmin, fmaf(-2.0f, acc[m][n][rg], cq[n]));
#pragma unroll
                    for (int off = 1; off <= 8; off <<= 1)
                        cmin = fminf(cmin, __shfl_xor(cmin, off, 16));
                    runmin[m][rg] = fminf(runmin[m][rg], cmin);
                    float thr = runmin[m][rg] + MARGIN;
                    int lrow = arow_base + m * 16 + l4 * 4 + rg;
#pragma unroll
                    for (int n = 0; n < 4; ++n) {
                        float d = fmaf(-2.0f, acc[m][n][rg], cq[n]);
                        if (d <= thr) {
                            int slot = atomicAdd(&lcnt, 1);
                            if (slot < LIST_CAP)
                                list[slot] = ((u32)lrow << 10) |
                                             (u32)(e0 + wn * 64 + n * 16 + l15);
                        }
                    }
                }
            }
        }
    }
    __syncthreads();

    // ---- exact f32 refinement (128 groups of 4 lanes; 32 loads in flight each)
    int nlist = lcnt < LIST_CAP ? lcnt : LIST_CAP;
    const int grp = tid >> 2, gl = tid & 3;
    for (int i = grp; i < nlist; i += 128) {
        u32 ent = list[i];
        int lrow = ent >> 10, code = ent & 1023;
        const float4* zr = (const float4*)(z + (size_t)(row0 + lrow) * DIM);
        const float4* cr = (const float4*)(cb + (size_t)code * DIM);
        float s = 0.f;
#pragma unroll
        for (int j = 0; j < 16; ++j) {
            float4 zv = zr[j * 4 + gl];
            float4 cv = cr[j * 4 + gl];
            s = fmaf(zv.x, cv.x, s); s = fmaf(zv.y, cv.y, s);
            s = fmaf(zv.z, cv.z, s); s = fmaf(zv.w, cv.w, s);
        }
        s += __shfl_xor(s, 1, 4);
        s += __shfl_xor(s, 2, 4);
        if (gl == 0) {
            float d = fmaf(-2.0f, s, csq_s[code]);
            u32 bb = __float_as_uint(d);
            u32 mm = (bb & 0x80000000u) ? ~bb : (bb | 0x80000000u);
            u64 key = ((u64)mm << 10) | (u32)code;
            atomicMin(&keys[row0 + lrow], key);
        }
    }
    __syncthreads();

    // ---- winners: idx + counts + loss (exact dist from key + ||z||^2)
    float lsum = 0.f;
    if (tid < 128) {
        u64 key = atomicMin(&keys[row0 + tid], ~0ull);   // L2-coherent readback
        int idx = (int)(key & 1023u);
        u32 mm = (u32)(key >> 10);
        u32 bb = (mm & 0x80000000u) ? (mm & 0x7fffffffu) : ~mm;
        float dist = __uint_as_float(bb);                // c^2 - 2 z.c (exact f32)
        lsum = fmaxf(dist + zsq_s[tid], 0.f);            // ||z - c||^2
        out_idx[row0 + tid] = (float)idx;
        wsi[OFF_IDX + row0 + tid] = idx;
        atomicAdd(&ws[OFF_CNT + idx], 1.0f);
    }
#pragma unroll
    for (int off = 32; off >= 1; off >>= 1) lsum += __shfl_down(lsum, off, 64);
    if ((tid & 63) == 0) lred[tid >> 6] = lsum;
    __syncthreads();
    if (tid == 0) {
        float t = 0.f;
#pragma unroll
        for (int w = 0; w < 8; ++w) t += lred[w];
        atomicAdd(&ws[OFF_LOSS], t);
    }
}

// ---------------- post (cooperative): gather + EMA/scan + scatter + segsum + codebook ----------------
__global__ __launch_bounds__(512) void post_kernel(const float* __restrict__ z,
                                                   const float* __restrict__ cb,
                                                   const float* __restrict__ ema_cs,
                                                   const float* __restrict__ ema_sum,
                                                   float* __restrict__ ws,
                                                   float* __restrict__ out) {
    cg::grid_group grid = cg::this_grid();
    __shared__ float wred[8];
    __shared__ int   wscan[8];
    __shared__ int   srow2[2][32];
    __shared__ int   scode2[2][32];

    const int tid = threadIdx.x, bid = blockIdx.x;
    int* wsi = (int*)ws;
    float* bsum = out + O_NES;

    // ---- stage A: gather z_q = cb[idx] (128 rows/block, 4 threads/row)
    {
        int r = bid * 128 + (tid >> 2), part = tid & 3;
        int e = wsi[OFF_IDX + r];
        const float4* crow = (const float4*)(cb + (size_t)e * DIM) + part * 16;
        float4*       qrow = (float4*)(out + O_ZQ + (size_t)r * DIM) + part * 16;
#pragma unroll
        for (int j = 0; j < 16; ++j) qrow[j] = crow[j];
    }
    grid.sync();

    // ---- stage B: block 0: ncs EMA, n, loss, exclusive scan of counts
    if (bid == 0) {
        const int lane = tid & 63, w = tid >> 6;
        float c0 = ws[OFF_CNT + 2 * tid], c1 = ws[OFF_CNT + 2 * tid + 1];
        float ncs0 = 0.99f * ema_cs[2 * tid] + 0.01f * c0;
        float ncs1 = 0.99f * ema_cs[2 * tid + 1] + 0.01f * c1;
        out[O_NCS + 2 * tid] = ncs0;
        out[O_NCS + 2 * tid + 1] = ncs1;

        float s = ncs0 + ncs1;
#pragma unroll
        for (int off = 32; off >= 1; off >>= 1) s += __shfl_down(s, off, 64);

        int pair = (int)c0 + (int)c1;
        int x = pair;
#pragma unroll
        for (int off = 1; off < 64; off <<= 1) {
            int o = __shfl_up(x, off, 64);
            if (lane >= off) x += o;
        }
        if (lane == 63) wscan[w] = x;
        if (lane == 0)  wred[w]  = s;
        __syncthreads();
        if (tid == 0) {
            float n = 0.f;
#pragma unroll
            for (int k = 0; k < 8; ++k) n += wred[k];
            ws[OFF_N] = n;
            out[O_LOSS] = 0.5f * ws[OFF_LOSS] / 8388608.0f;
            int run = 0;
#pragma unroll
            for (int k = 0; k < 8; ++k) { int t = wscan[k]; wscan[k] = run; run += t; }
        }
        __syncthreads();
        int base_pair = x - pair + wscan[w];
        wsi[OFF_BASE + 2 * tid]     = base_pair;
        wsi[OFF_BASE + 2 * tid + 1] = base_pair + (int)c0;
    }
    grid.sync();

    // ---- stage C: scatter row ids into per-code buckets
    {
        int g = bid * 512 + tid;
        if (g < N_ROWS) {
            int e = wsi[OFF_IDX + g];
            int slot = atomicAdd(&wsi[OFF_FILL + e], 1);
            wsi[OFF_BUCKET + wsi[OFF_BASE + e] + slot] = g;
        }
    }
    grid.sync();

    // ---- stage D: segmented embed-sum over bucket array (4 chunks of 32 per block)
#pragma unroll
    for (int s = 0; s < 2; ++s) {
        __syncthreads();
        if (tid < 64) {
            int sub = tid >> 5, i = tid & 31;
            int ck = bid * 4 + s * 2 + sub;
            int row = wsi[OFF_BUCKET + ck * 32 + i];
            srow2[sub][i]  = row;
            scode2[sub][i] = wsi[OFF_IDX + row];
        }
        __syncthreads();
        int sub = tid >> 8, d = tid & 255;
        float acc = 0.f;
        int prev = scode2[sub][0];
#pragma unroll 4
        for (int i = 0; i < 32; ++i) {
            int e = scode2[sub][i];
            if (e != prev) {
                atomicAdd(&bsum[(size_t)prev * DIM + d], acc);
                acc = 0.f;
                prev = e;
            }
            acc += z[(size_t)srow2[sub][i] * DIM + d];
        }
        atomicAdd(&bsum[(size_t)prev * DIM + d], acc);
    }
    grid.sync();

    // ---- stage E: embed-sum EMA + smoothed codebook
    {
        float n = ws[OFF_N];
#pragma unroll
        for (int s = 0; s < 2; ++s) {
            int e = bid * 4 + s * 2 + (tid >> 8);
            int d = tid & 255;
            size_t i = (size_t)e * DIM + d;
            float bs  = bsum[i];
            float nes = 0.99f * ema_sum[i] + 0.01f * bs;
            out[O_NES + i] = nes;
            float ncs = out[O_NCS + e];
            float sm  = (ncs + 1e-5f) / (n + NE * 1e-5f) * n;
            out[O_NCB + i] = nes / sm;
        }
    }
}

extern "C" void kernel_launch(void* const* d_in, const int* in_sizes, int n_in,
                              void* d_out, int out_size, void* d_ws, size_t ws_size,
                              hipStream_t stream) {
    const float* z_e      = (const float*)d_in[0];
    const float* codebook = (const float*)d_in[1];
    const float* ema_cs   = (const float*)d_in[2];
    const float* ema_sum  = (const float*)d_in[3];
    float* out = (float*)d_out;
    float* ws  = (float*)d_ws;

    prep_kernel<<<256, 256, 0, stream>>>(codebook, ws, out + O_NES);

    vq_main<<<256, 512, 0, stream>>>(z_e, codebook, ws, out + O_IDX);

    void* pargs[6];
    pargs[0] = (void*)&z_e;
    pargs[1] = (void*)&codebook;
    pargs[2] = (void*)&ema_cs;
    pargs[3] = (void*)&ema_sum;
    pargs[4] = (void*)&ws;
    pargs[5] = (void*)&out;
    hipLaunchCooperativeKernel((const void*)post_kernel, dim3(256), dim3(512),
                               pargs, 0, stream);
}

// Round 8
// 274.425 us; speedup vs baseline: 1.2820x; 1.2820x over previous
//
#include <hip/hip_runtime.h>

typedef unsigned long long u64;
typedef unsigned int u32;
typedef __attribute__((ext_vector_type(8))) short short8;
typedef __attribute__((ext_vector_type(4))) float f32x4;

#define N_ROWS 32768
#define DIM    256
#define NE     1024

// out layout (float offsets)
#define O_ZQ   0
#define O_LOSS 8388608
#define O_IDX  8388609
#define O_NCB  8421377
#define O_NCS  8683521
#define O_NES  8684545

// ws layout (float offsets)
#define OFF_LOSS   0
#define OFF_N      1
#define OFF_DONE   2         // int: blocks-finished counter
#define OFF_CSQ    64
#define OFF_CNT    1088
#define OFF_FILL   2112      // int[1024]
#define OFF_BASE   3200      // int[1024]
#define OFF_IDX    4224      // int[32768]
#define OFF_BUCKET 36992     // int[32768]
#define OFF_KEY    69888     // u64[32768]
#define OFF_CB16   135424    // ushort[262144] = 512KB bf16 codebook

#define MARGIN   2.0f
#define LIST_CAP 3072

__device__ __forceinline__ unsigned short bf16rne(float x) {
    u32 b = __float_as_uint(x);
    return (unsigned short)((b + 0x7FFFu + ((b >> 16) & 1u)) >> 16);
}

// ---------------- prep: zero stats/keys/bsum + csq + bf16 codebook ----------------
__global__ __launch_bounds__(256) void prep_kernel(const float* __restrict__ cb,
                                                   float* __restrict__ ws,
                                                   float* __restrict__ out_nes) {
    const int tid = threadIdx.x, b = blockIdx.x;
    const int g = b * 256 + tid;

#pragma unroll
    for (int j = 0; j < 4; ++j) out_nes[g + j * 65536] = 0.f;
    if (g < N_ROWS) ((u64*)(ws + OFF_KEY))[g] = ~0ull;
    if (g < 2048) ws[OFF_CNT + g] = 0.f;           // CNT + FILL
    if (g == 0) { ws[OFF_LOSS] = 0.f; ((int*)ws)[OFF_DONE] = 0; }

    const int e = b * 4 + (tid >> 6);
    const int lane = tid & 63;
    float4 v = *(const float4*)(cb + (size_t)e * DIM + lane * 4);
    ushort4 h;
    h.x = bf16rne(v.x); h.y = bf16rne(v.y); h.z = bf16rne(v.z); h.w = bf16rne(v.w);
    *(ushort4*)((unsigned short*)(ws + OFF_CB16) + (size_t)e * DIM + lane * 4) = h;
    float s = v.x * v.x + v.y * v.y + v.z * v.z + v.w * v.w;
#pragma unroll
    for (int off = 32; off >= 1; off >>= 1) s += __shfl_down(s, off, 64);
    if (lane == 0) ws[OFF_CSQ + e] = s;
}

// ---- main: MFMA distances + refine + gather + stats + last-block finalize ----
__global__ __launch_bounds__(512, 2) void vq_main(const float* __restrict__ z,
                                                  const float* __restrict__ cb,
                                                  const float* __restrict__ ema_cs,
                                                  float* __restrict__ ws,
                                                  float* __restrict__ out_zq,
                                                  float* __restrict__ out_idx,
                                                  float* __restrict__ out_ncs,
                                                  float* __restrict__ out_loss) {
    __shared__ unsigned short zs[128][256];   // 64KB, cols XOR-swizzled by 8*(row&15)
    __shared__ unsigned short cbs[256][128];  // 64KB, same swizzle
    __shared__ float csq_s[NE];               // 4KB
    __shared__ u32   list[LIST_CAP];          // 12KB
    __shared__ int   lcnt;
    __shared__ float zsq_s[128];
    __shared__ int   sidx[128];
    __shared__ float lred[8];
    __shared__ int   lastflag;
    __shared__ float wred[8];
    __shared__ int   wscan[8];

    const int tid  = threadIdx.x;
    const int row0 = blockIdx.x * 128;
    const unsigned short* cb16 = (const unsigned short*)(ws + OFF_CB16);
    u64* keys = (u64*)(ws + OFF_KEY);
    int* wsi  = (int*)ws;

    // ---- prologue: issue cbs tile-0 loads first (they fly during z staging)
    const int sr_c = tid >> 4;            // 0..31
    const int lk_c = (tid & 15) * 8;
    short8 stg[8];
#pragma unroll
    for (int s = 0; s < 8; ++s)
        stg[s] = *(const short8*)(cb16 + (size_t)(s * 32 + sr_c) * DIM + lk_c);

    if (tid == 0) lcnt = 0;
    if (tid < 128) zsq_s[tid] = 0.f;
    csq_s[tid]       = ws[OFF_CSQ + tid];
    csq_s[tid + 512] = ws[OFF_CSQ + tid + 512];
    __syncthreads();   // zsq_s zeroed before atomic accumulation

    // ---- stage z tile f32 -> bf16 (+ per-row ||z||^2 accumulation)
#pragma unroll
    for (int sweep = 0; sweep < 8; ++sweep) {
        int fi = sweep * 4096 + tid * 8;
        int r = fi >> 8, c = fi & 255;
        const float4* src = (const float4*)(z + (size_t)row0 * DIM + fi);
        float4 v0 = src[0], v1 = src[1];
        short8 p;
        p[0] = (short)bf16rne(v0.x); p[1] = (short)bf16rne(v0.y);
        p[2] = (short)bf16rne(v0.z); p[3] = (short)bf16rne(v0.w);
        p[4] = (short)bf16rne(v1.x); p[5] = (short)bf16rne(v1.y);
        p[6] = (short)bf16rne(v1.z); p[7] = (short)bf16rne(v1.w);
        *(short8*)&zs[r][c ^ (8 * (r & 15))] = p;
        float sq = v0.x * v0.x + v0.y * v0.y + v0.z * v0.z + v0.w * v0.w
                 + v1.x * v1.x + v1.y * v1.y + v1.z * v1.z + v1.w * v1.w;
        atomicAdd(&zsq_s[r], sq);
    }

    const int wid = tid >> 6, lane = tid & 63;
    const int wm = wid >> 2, wn = wid & 3;          // wave grid 2M x 4N
    const int l15 = lane & 15, l4 = lane >> 4;
    const int arow_base = wm * 64;
    const int swz = 8 * l15;

    float runmin[4][4];
#pragma unroll
    for (int m = 0; m < 4; ++m)
#pragma unroll
        for (int rg = 0; rg < 4; ++rg) runmin[m][rg] = 3.4e38f;

    f32x4 acc[4][4];

    // ---- 8 phases (4 chunks x 2 k-halves), cbs staged one phase ahead
    for (int phase = 0; phase < 8; ++phase) {
        const int chunk = phase >> 1, kh = phase & 1;
        const int e0 = chunk << 8;
        if (kh == 0) {
#pragma unroll
            for (int m = 0; m < 4; ++m)
#pragma unroll
                for (int n = 0; n < 4; ++n) acc[m][n] = (f32x4){0.f, 0.f, 0.f, 0.f};
        }
        __syncthreads();   // previous tile's readers done
#pragma unroll
        for (int s = 0; s < 8; ++s) {          // ds_write staged regs (vmcnt wait here)
            int r = s * 32 + sr_c;
            *(short8*)&cbs[r][lk_c ^ (8 * (r & 15))] = stg[s];
        }
        __syncthreads();   // tile visible
        if (phase < 7) {                        // issue next tile's loads (async)
            int np = phase + 1;
            int nbase = (np >> 1) * 256, nkh = np & 1;
#pragma unroll
            for (int s = 0; s < 8; ++s)
                stg[s] = *(const short8*)(cb16 + (size_t)(nbase + s * 32 + sr_c) * DIM
                                          + nkh * 128 + lk_c);
        }
#pragma unroll
        for (int ks = 0; ks < 4; ++ks) {
            short8 a[4], bfr[4];
            int acol = kh * 128 + ks * 32 + 8 * l4;
            int bcol = ks * 32 + 8 * l4;
#pragma unroll
            for (int m = 0; m < 4; ++m)
                a[m] = *(const short8*)&zs[arow_base + m * 16 + l15][acol ^ swz];
#pragma unroll
            for (int n = 0; n < 4; ++n)
                bfr[n] = *(const short8*)&cbs[wn * 64 + n * 16 + l15][bcol ^ swz];
#pragma unroll
            for (int m = 0; m < 4; ++m)
#pragma unroll
                for (int n = 0; n < 4; ++n)
                    acc[m][n] = __builtin_amdgcn_mfma_f32_16x16x32_bf16(
                        a[m], bfr[n], acc[m][n], 0, 0, 0);
        }
        if (kh == 1) {
            // ---- chunk epilogue: per-row running min + margin push
            float cq[4];
#pragma unroll
            for (int n = 0; n < 4; ++n) cq[n] = csq_s[e0 + wn * 64 + n * 16 + l15];
#pragma unroll
            for (int m = 0; m < 4; ++m) {
#pragma unroll
                for (int rg = 0; rg < 4; ++rg) {
                    float cmin = 3.4e38f;
#pragma unroll
                    for (int n = 0; n < 4; ++n)
                        cmin = fminf(cmin, fmaf(-2.0f, acc[m][n][rg], cq[n]));
#pragma unroll
                    for (int off = 1; off <= 8; off <<= 1)
                        cmin = fminf(cmin, __shfl_xor(cmin, off, 16));
                    runmin[m][rg] = fminf(runmin[m][rg], cmin);
                    float thr = runmin[m][rg] + MARGIN;
                    int lrow = arow_base + m * 16 + l4 * 4 + rg;
#pragma unroll
                    for (int n = 0; n < 4; ++n) {
                        float d = fmaf(-2.0f, acc[m][n][rg], cq[n]);
                        if (d <= thr) {
                            int slot = atomicAdd(&lcnt, 1);
                            if (slot < LIST_CAP)
                                list[slot] = ((u32)lrow << 10) |
                                             (u32)(e0 + wn * 64 + n * 16 + l15);
                        }
                    }
                }
            }
        }
    }
    __syncthreads();

    // ---- exact f32 refinement (128 groups of 4 lanes; 32 loads in flight each)
    int nlist = lcnt < LIST_CAP ? lcnt : LIST_CAP;
    const int grp = tid >> 2, gl = tid & 3;
    for (int i = grp; i < nlist; i += 128) {
        u32 ent = list[i];
        int lrow = ent >> 10, code = ent & 1023;
        const float4* zr = (const float4*)(z + (size_t)(row0 + lrow) * DIM);
        const float4* cr = (const float4*)(cb + (size_t)code * DIM);
        float s = 0.f;
#pragma unroll
        for (int j = 0; j < 16; ++j) {
            float4 zv = zr[j * 4 + gl];
            float4 cv = cr[j * 4 + gl];
            s = fmaf(zv.x, cv.x, s); s = fmaf(zv.y, cv.y, s);
            s = fmaf(zv.z, cv.z, s); s = fmaf(zv.w, cv.w, s);
        }
        s += __shfl_xor(s, 1, 4);
        s += __shfl_xor(s, 2, 4);
        if (gl == 0) {
            float d = fmaf(-2.0f, s, csq_s[code]);
            u32 bb = __float_as_uint(d);
            u32 mm = (bb & 0x80000000u) ? ~bb : (bb | 0x80000000u);
            u64 key = ((u64)mm << 10) | (u32)code;
            atomicMin(&keys[row0 + lrow], key);
        }
    }
    __syncthreads();

    // ---- winners: idx + counts + loss (exact dist from key + ||z||^2)
    float lsum = 0.f;
    if (tid < 128) {
        u64 key = atomicMin(&keys[row0 + tid], ~0ull);   // L2-coherent readback
        int idx = (int)(key & 1023u);
        u32 mm = (u32)(key >> 10);
        u32 bb = (mm & 0x80000000u) ? (mm & 0x7fffffffu) : ~mm;
        float dist = __uint_as_float(bb);                // c^2 - 2 z.c (exact f32)
        lsum = fmaxf(dist + zsq_s[tid], 0.f);            // ||z - c||^2
        sidx[tid] = idx;
        out_idx[row0 + tid] = (float)idx;
        wsi[OFF_IDX + row0 + tid] = idx;
        atomicAdd(&ws[OFF_CNT + idx], 1.0f);
    }
    __syncthreads();

    // ---- gather z_q = cb[idx] (4 threads/row; cb is L2-resident)
    {
        int r = tid >> 2, part = tid & 3;
        int e = sidx[r];
        const float4* crow = (const float4*)(cb + (size_t)e * DIM) + part * 16;
        float4*       qrow = (float4*)(out_zq + (size_t)(row0 + r) * DIM) + part * 16;
#pragma unroll
        for (int j = 0; j < 16; ++j) qrow[j] = crow[j];
    }

    // ---- loss reduction
#pragma unroll
    for (int off = 32; off >= 1; off >>= 1) lsum += __shfl_down(lsum, off, 64);
    if ((tid & 63) == 0) lred[tid >> 6] = lsum;
    __syncthreads();
    if (tid == 0) {
        float t = 0.f;
#pragma unroll
        for (int w = 0; w < 8; ++w) t += lred[w];
        atomicAdd(&ws[OFF_LOSS], t);
    }
    __syncthreads();

    // ---- last block finishes: counts EMA + n + loss + exclusive scan -> BASE
    __threadfence();
    if (tid == 0)
        lastflag = (atomicAdd(&wsi[OFF_DONE], 1) == 255) ? 1 : 0;
    __syncthreads();
    if (!lastflag) return;

    {
        const int ln = tid & 63, w = tid >> 6;
        float c0 = atomicAdd(&ws[OFF_CNT + 2 * tid], 0.f);      // coherent readback
        float c1 = atomicAdd(&ws[OFF_CNT + 2 * tid + 1], 0.f);
        float ncs0 = 0.99f * ema_cs[2 * tid] + 0.01f * c0;
        float ncs1 = 0.99f * ema_cs[2 * tid + 1] + 0.01f * c1;
        out_ncs[2 * tid]     = ncs0;
        out_ncs[2 * tid + 1] = ncs1;

        float s = ncs0 + ncs1;
#pragma unroll
        for (int off = 32; off >= 1; off >>= 1) s += __shfl_down(s, off, 64);

        int pair = (int)c0 + (int)c1;
        int x = pair;
#pragma unroll
        for (int off = 1; off < 64; off <<= 1) {
            int o = __shfl_up(x, off, 64);
            if (ln >= off) x += o;
        }
        if (ln == 63) wscan[w] = x;
        if (ln == 0)  wred[w]  = s;
        __syncthreads();
        if (tid == 0) {
            float n = 0.f;
#pragma unroll
            for (int k = 0; k < 8; ++k) n += wred[k];
            ws[OFF_N] = n;
            float lossv = atomicAdd(&ws[OFF_LOSS], 0.f);
            out_loss[0] = 0.5f * lossv / 8388608.0f;
            int run = 0;
#pragma unroll
            for (int k = 0; k < 8; ++k) { int t = wscan[k]; wscan[k] = run; run += t; }
        }
        __syncthreads();
        int base_pair = x - pair + wscan[w];
        wsi[OFF_BASE + 2 * tid]     = base_pair;
        wsi[OFF_BASE + 2 * tid + 1] = base_pair + (int)c0;
    }
}

// ---------------- scatter: block-aggregated bucket fill (low contention) ----------------
__global__ __launch_bounds__(512) void scatter_kernel(float* __restrict__ ws) {
    __shared__ int hist[NE];
    __shared__ int bbase[NE];
    const int tid = threadIdx.x, bid = blockIdx.x;
    int* wsi = (int*)ws;

    for (int c = tid; c < NE; c += 512) hist[c] = 0;
    __syncthreads();

    int g = bid * 512 + tid;
    int e = wsi[OFF_IDX + g];
    int rank = atomicAdd(&hist[e], 1);          // LDS
    __syncthreads();

    for (int c = tid; c < NE; c += 512) {
        int h = hist[c];
        if (h) bbase[c] = atomicAdd(&wsi[OFF_FILL + c], h);   // <=64 hits per address
    }
    __syncthreads();

    wsi[OFF_BUCKET + wsi[OFF_BASE + e] + bbase[e] + rank] = g;
}

// ---------------- work-balanced segmented embed-sum over bucket array ----------------
__global__ __launch_bounds__(256) void seg_reduce(const float* __restrict__ z,
                                                  const float* __restrict__ ws,
                                                  float* __restrict__ bsum) {
    __shared__ int srow[32];
    __shared__ int scode[32];
    const int tid = threadIdx.x;
    const int p0  = blockIdx.x * 32;
    const int* wsi = (const int*)ws;

    if (tid < 32) {
        int row = wsi[OFF_BUCKET + p0 + tid];
        srow[tid]  = row;
        scode[tid] = wsi[OFF_IDX + row];
    }
    __syncthreads();

    const int d = tid;
    float acc = 0.f;
    int prev = scode[0];
#pragma unroll 4
    for (int i = 0; i < 32; ++i) {
        int e = scode[i];
        if (e != prev) {
            atomicAdd(&bsum[(size_t)prev * DIM + d], acc);
            acc = 0.f;
            prev = e;
        }
        acc += z[(size_t)srow[i] * DIM + d];
    }
    atomicAdd(&bsum[(size_t)prev * DIM + d], acc);
}

// ---------------- EMA + smoothed codebook (bsum accumulated in out_nes) ----------------
__global__ __launch_bounds__(256) void finalize_b(const float* __restrict__ ema_sum,
                                                  const float* __restrict__ ws,
                                                  const float* __restrict__ out_ncs,
                                                  float* __restrict__ out_nes,
                                                  float* __restrict__ out_ncb) {
    const int e = blockIdx.x, d = threadIdx.x;
    const size_t i = (size_t)e * DIM + d;
    float bsum = out_nes[i];
    float nes  = 0.99f * ema_sum[i] + 0.01f * bsum;
    out_nes[i] = nes;
    float ncs = out_ncs[e];
    float n   = ws[OFF_N];
    float sm  = (ncs + 1e-5f) / (n + NE * 1e-5f) * n;
    out_ncb[i] = nes / sm;
}

extern "C" void kernel_launch(void* const* d_in, const int* in_sizes, int n_in,
                              void* d_out, int out_size, void* d_ws, size_t ws_size,
                              hipStream_t stream) {
    const float* z_e      = (const float*)d_in[0];
    const float* codebook = (const float*)d_in[1];
    const float* ema_cs   = (const float*)d_in[2];
    const float* ema_sum  = (const float*)d_in[3];
    float* out = (float*)d_out;
    float* ws  = (float*)d_ws;

    prep_kernel<<<256, 256, 0, stream>>>(codebook, ws, out + O_NES);

    vq_main<<<256, 512, 0, stream>>>(z_e, codebook, ema_cs, ws,
                                     out + O_ZQ, out + O_IDX,
                                     out + O_NCS, out + O_LOSS);

    scatter_kernel<<<N_ROWS / 512, 512, 0, stream>>>(ws);

    seg_reduce<<<N_ROWS / 32, 256, 0, stream>>>(z_e, ws, out + O_NES);

    finalize_b<<<NE, 256, 0, stream>>>(ema_sum, ws, out + O_NCS,
                                       out + O_NES, out + O_NCB);
}